// Round 6
// baseline (35.969 us; speedup 1.0000x reference)
//
#include <hip/hip_runtime.h>

#define Bz 4
#define Nn 1024
#define Cc 23
#define Hh 100
#define KNOTS 257            // v = r/1.5 tabulated on [0,3], 256 cells
#define DSTRIDE 264          // floats per D row (257 padded, 1056B = 66*16)

// ws float offsets
#define D_OFF     0                 // [4][1024][264] = 1081344
#define G4_OFF    1081344           // [4096][4] = 16384
#define BIAS_OFF  1097728           // [4]
#define CONV_OFF  1097732           // [4][1024] = 4096 (atomic accumulator)

// ---------------------------------------------------------------------------
// Kernel A: fused prep + dgemm.
//  blocks 0..159  : per-block U-row recompute (64 knots, 4-lane h-split) then
//                   D[zb][k] = sum_c U[k][c]*f[zb][c] for a 128-zb chunk
//  blocks 160..175: geom4 pack
//  blocks 176..179: bias[z] = sum_b sum_c b2[c] f[z][b][c]
//  block  180     : zero conv accumulator
// ---------------------------------------------------------------------------
__global__ __launch_bounds__(256)
void prep_dgemm_kernel(const float* __restrict__ f,
                       const float* __restrict__ geom,
                       const float* __restrict__ W1,
                       const float* __restrict__ b1,
                       const float* __restrict__ W2,
                       const float* __restrict__ b2,
                       float* __restrict__ ws) {
    int blk = blockIdx.x;
    int t = threadIdx.x;
    if (blk < 160) {
        __shared__ float up[4][64][25];     // h-split partials (pad 25: no conflicts)
        int kg = blk % 5;                   // knot group (64 knots)
        int zc = blk / 5;                   // zb chunk (128 rows)
        int lane = t & 63;
        int wv = __builtin_amdgcn_readfirstlane(t >> 6);   // wave id, SGPR
        int k = kg * 64 + lane;
        float v = (float)k * (3.0f / 256.0f);
        const float HPI = 1.57079632679f;
        float c0 = cosf(HPI * v);
        float c1 = cosf(HPI * (v - 1.0f));
        float c2 = cosf(HPI * (v - 2.0f));
        float s0 = (v < 1.0f) ? c0 * c0 : 0.0f;
        float s1 = (fabsf(v - 1.0f) < 1.0f) ? c1 * c1 : 0.0f;
        float s2 = (fabsf(v - 2.0f) < 1.0f) ? c2 * c2 : 0.0f;
        float uacc[Cc];
        #pragma unroll
        for (int c = 0; c < Cc; ++c) uacc[c] = 0.f;
        int h0 = wv * 25;
        #pragma unroll 5
        for (int h = h0; h < h0 + 25; ++h) {
            float hh = fmaxf(fmaf(s0, W1[h],
                              fmaf(s1, W1[Hh + h],
                               fmaf(s2, W1[2 * Hh + h], b1[h]))), 0.f);
            #pragma unroll
            for (int c = 0; c < Cc; ++c)
                uacc[c] = fmaf(hh, W2[h * Cc + c], uacc[c]);
        }
        #pragma unroll
        for (int c = 0; c < Cc; ++c) up[wv][lane][c] = uacc[c];
        __syncthreads();
        float ur[Cc];
        #pragma unroll
        for (int c = 0; c < Cc; ++c)
            ur[c] = (up[0][lane][c] + up[1][lane][c]) +
                    (up[2][lane][c] + up[3][lane][c]);
        // dgemm over this wave's 32 zb rows
        int zb0 = zc * 128 + wv * 32;
        float* Dp = ws + D_OFF;
        bool act = k < KNOTS;
        #pragma unroll 4
        for (int i = 0; i < 32; ++i) {
            const float* frow = f + (zb0 + i) * Cc;     // wave-uniform -> s_load
            float a0 = 0.f, a1 = 0.f, a2 = 0.f, a3 = 0.f;
            #pragma unroll
            for (int c = 0; c < 20; c += 4) {
                a0 = fmaf(frow[c + 0], ur[c + 0], a0);
                a1 = fmaf(frow[c + 1], ur[c + 1], a1);
                a2 = fmaf(frow[c + 2], ur[c + 2], a2);
                a3 = fmaf(frow[c + 3], ur[c + 3], a3);
            }
            a0 = fmaf(frow[20], ur[20], a0);
            a1 = fmaf(frow[21], ur[21], a1);
            a2 = fmaf(frow[22], ur[22], a2);
            if (act) Dp[(zb0 + i) * DSTRIDE + k] = (a0 + a1) + (a2 + a3);
        }
    } else if (blk < 176) {                // geom4
        int zb = (blk - 160) * 256 + t;
        const float* g = geom + zb * 3;
        reinterpret_cast<float4*>(ws + G4_OFF)[zb] =
            make_float4(g[0], g[1], g[2], 0.f);
    } else if (blk < 180) {                // bias
        int z = blk - 176;
        float s = 0.f;
        for (int b = t; b < Nn; b += 256) {
            const float* frow = f + (z * Nn + b) * Cc;
            #pragma unroll
            for (int c = 0; c < Cc; ++c) s = fmaf(frow[c], b2[c], s);
        }
        __shared__ float red[256];
        red[t] = s; __syncthreads();
        for (int off = 128; off; off >>= 1) {
            if (t < off) red[t] += red[t + off];
            __syncthreads();
        }
        if (t == 0) ws[BIAS_OFF + z] = red[0];
    } else {                               // zero conv accumulator
        float4 zv = make_float4(0.f, 0.f, 0.f, 0.f);
        #pragma unroll
        for (int j = 0; j < 4; ++j)
            reinterpret_cast<float4*>(ws + CONV_OFF)[j * 256 + t] = zv;
    }
}

// ---------------------------------------------------------------------------
// conv: grid = z(4) x aq(4) x s(32) = 512 blocks x 256 threads (thread = a).
// Stage 32 D rows (33.8 KB) once; 32 lerp edges per thread; atomicAdd result.
// ---------------------------------------------------------------------------
__global__ __launch_bounds__(256, 2)
void conv_kernel(const float4* __restrict__ geom4,   // ws + G4_OFF
                 const float* __restrict__ D,        // ws + D_OFF
                 float* __restrict__ convp) {        // ws + CONV_OFF
    __shared__ float lds[32 * DSTRIDE];   // 33792 B
    int bid = blockIdx.x;
    int s = bid & 31;
    int aq = (bid >> 5) & 3;
    int z = bid >> 7;
    int t = threadIdx.x;
    int b0 = s * 32;

    const float4* src = reinterpret_cast<const float4*>(D + (z * Nn + b0) * DSTRIDE);
    for (int j = t; j < 32 * DSTRIDE / 4; j += 256)
        reinterpret_cast<float4*>(lds)[j] = src[j];
    float4 ga = geom4[z * Nn + aq * 256 + t];
    __syncthreads();

    float acc = 0.f;
    #pragma unroll 8
    for (int bl = 0; bl < 32; ++bl) {
        float4 gb = geom4[z * Nn + b0 + bl];          // uniform -> s_load
        float dx = ga.x - gb.x, dy = ga.y - gb.y, dz = ga.z - gb.z;
        float r = sqrtf(fmaf(dx, dx, fmaf(dy, dy, fmaf(dz, dz, 1e-12f))));
        float mu = fminf(r * 56.8888889f, 255.999f);  // v*256/3, clamped
        int m = (int)mu;
        float tt = mu - (float)m;
        const float* row = lds + bl * DSTRIDE + m;
        float d0 = row[0];
        float d1 = row[1];
        acc += fmaf(tt, d1 - d0, d0);
    }
    atomicAdd(&convp[(z << 10) + aq * 256 + t], acc);
}

// ---------------------------------------------------------------------------
// head: one 960-thread block. fc1 (8 k-strips x 120 (z,d) pairs) -> fc2 -> fc3
// ---------------------------------------------------------------------------
__global__ __launch_bounds__(960)
void head_kernel(const float* __restrict__ ws,
                 const float* __restrict__ Wf1, const float* __restrict__ bf1,
                 const float* __restrict__ Wf2, const float* __restrict__ bf2,
                 const float* __restrict__ Wf3, const float* __restrict__ bf3,
                 float* __restrict__ out) {
    __shared__ float red[120][8];
    __shared__ float x1s[120];
    __shared__ float x2s[40];
    int t = threadIdx.x;
    int pair = t % 120;
    int strip = t / 120;
    int z = pair / 30, d = pair % 30;
    float biasz = ws[BIAS_OFF + z];
    const float* cz = ws + CONV_OFF + (z << 10);
    float acc = 0.f;
    int k0 = strip * 128;
    #pragma unroll 4
    for (int i = 0; i < 128; ++i) {
        int k = k0 + i;
        float x = (cz[k] + biasz) * 0.03125f;
        acc = fmaf(x, Wf1[k * 30 + d], acc);
    }
    red[pair][strip] = acc;
    __syncthreads();
    if (t < 120) {
        float s = 0.f;
        #pragma unroll
        for (int j = 0; j < 8; ++j) s += red[t][j];
        x1s[t] = fmaxf(s + bf1[t % 30], 0.f);
    }
    __syncthreads();
    if (t < 40) {
        int zz = t / 10, dd = t % 10;
        float s = bf2[dd];
        #pragma unroll
        for (int kk = 0; kk < 30; ++kk)
            s = fmaf(x1s[zz * 30 + kk], Wf2[kk * 10 + dd], s);
        x2s[t] = fmaxf(s, 0.f);
    }
    __syncthreads();
    if (t < Bz) {
        float s = bf3[0];
        #pragma unroll
        for (int kk = 0; kk < 10; ++kk)
            s = fmaf(x2s[t * 10 + kk], Wf3[kk], s);
        out[t] = s;
    }
}

extern "C" void kernel_launch(void* const* d_in, const int* in_sizes, int n_in,
                              void* d_out, int out_size, void* d_ws, size_t ws_size,
                              hipStream_t stream) {
    const float* f   = (const float*)d_in[0];
    const float* geo = (const float*)d_in[1];
    const float* W1  = (const float*)d_in[2];
    const float* b1  = (const float*)d_in[3];
    const float* W2  = (const float*)d_in[4];
    const float* b2  = (const float*)d_in[5];
    const float* Wf1 = (const float*)d_in[6];
    const float* bf1 = (const float*)d_in[7];
    const float* Wf2 = (const float*)d_in[8];
    const float* bf2 = (const float*)d_in[9];
    const float* Wf3 = (const float*)d_in[10];
    const float* bf3 = (const float*)d_in[11];
    float* ws  = (float*)d_ws;
    float* out = (float*)d_out;

    hipLaunchKernelGGL(prep_dgemm_kernel, dim3(181), dim3(256), 0, stream,
                       f, geo, W1, b1, W2, b2, ws);
    hipLaunchKernelGGL(conv_kernel, dim3(512), dim3(256), 0, stream,
                       reinterpret_cast<const float4*>(ws + G4_OFF),
                       ws + D_OFF, ws + CONV_OFF);
    hipLaunchKernelGGL(head_kernel, dim3(1), dim3(960), 0, stream,
                       ws, Wf1, bf1, Wf2, bf2, Wf3, bf3, out);
}